// Round 5
// baseline (273.575 us; speedup 1.0000x reference)
//
#include <hip/hip_runtime.h>
#include <cstddef>

#define K 64
#define D 768
#define D4 192   // D/4

__device__ __forceinline__ float d4f(float4 a, float4 b) {
  return a.x*b.x + a.y*b.y + a.z*b.z + a.w*b.w;
}
__device__ __forceinline__ float4 a4(float4 a, float4 b) {
  return make_float4(a.x+b.x, a.y+b.y, a.z+b.z, a.w+b.w);
}
__device__ __forceinline__ unsigned short f2bf(float x) {
  unsigned int u = __float_as_uint(x);
  unsigned int r = (u + 0x7FFFu + ((u >> 16) & 1u)) >> 16;
  return (unsigned short)r;
}

typedef __attribute__((ext_vector_type(8)))  short bf16x8;
typedef __attribute__((ext_vector_type(16))) float f32x16;

// =====================================================================
// FAST PATH (N=32768, NC=256, C=128)
// =====================================================================
#define NCF 256
#define CF  128

// ---- K1c: cast cavg to bf16 + exact ||row||^2 ----
__global__ __launch_bounds__(256) void k1c(
    const float* __restrict__ cavg, unsigned short* __restrict__ cavgb,
    float* __restrict__ cn2)
{
  int wave = blockIdx.x * 4 + (threadIdx.x >> 6);
  int l = threadIdx.x & 63;
  if (wave >= K) return;
  const float* src = cavg + (size_t)wave * D;
  unsigned short* dst = cavgb + (size_t)wave * D;
  float sq = 0.f;
#pragma unroll
  for (int t = 0; t < 3; ++t) {
    float4 v = ((const float4*)src)[t * 64 + l];
    sq += v.x*v.x + v.y*v.y + v.z*v.z + v.w*v.w;
    ushort4 o; o.x = f2bf(v.x); o.y = f2bf(v.y); o.z = f2bf(v.z); o.w = f2bf(v.w);
    ((ushort4*)dst)[t * 64 + l] = o;
  }
#pragma unroll
  for (int m = 1; m <= 32; m <<= 1) sq += __shfl_xor(sq, m);
  if (l == 0) cn2[wave] = sq;
}

// ---- K2: per-chunk per-class sums via LDS atomic adds (fire-and-forget) ----
// grid = 3 slabs x 256 chunks. Block: 256 threads, thread t owns column
// s*256+t. ds_add_f32 has no return -> no dependency chain; lanes hit
// consecutive banks (conflict-free); cross-wave collisions resolved by HW.
// Also emits Vb (bf16 cast of inputs) and per-chunk label counts.
__global__ __launch_bounds__(256) void k2_atomic(
    const float* __restrict__ inputs, const int* __restrict__ labels,
    unsigned short* __restrict__ Vb, float* __restrict__ sums,
    int* __restrict__ cnts_t)
{
  __shared__ float acc[K * 256];    // 64 KB
  __shared__ int   labL[128];
  __shared__ int   hist[K];
  const int bi = blockIdx.x;
  const int m = bi / 3, s = bi % 3;
  const int tid = threadIdx.x;

#pragma unroll
  for (int i = 0; i < 16; ++i)
    *(float4*)&acc[(i * 256 + tid) * 4] = make_float4(0.f, 0.f, 0.f, 0.f);
  if (tid < 128) labL[tid] = labels[m * 128 + tid];
  if (tid < K) hist[tid] = 0;
  __syncthreads();
  if (s == 0 && tid < 128) atomicAdd(&hist[labL[tid]], 1);

  const float* src = inputs + (size_t)m * 128 * D + s * 256 + tid;
  unsigned short* vdst = Vb + (size_t)m * 128 * D + s * 256 + tid;
#pragma unroll 8
  for (int j = 0; j < 128; ++j) {
    float v = src[(size_t)j * D];
    int lab = labL[j];
    atomicAdd(&acc[lab * 256 + tid], v);
    vdst[(size_t)j * D] = f2bf(v);
  }
  __syncthreads();

  float* sp = sums + (size_t)m * (K * D) + s * 256 + tid;
  for (int k = 0; k < K; ++k) sp[(size_t)k * D] = acc[k * 256 + tid];
  if (s == 0 && tid < K) cnts_t[tid * NCF + m] = hist[tid];
}

// ---- K2b: exclusive scan of transposed counts ----
__global__ void k2b_scan_cnts(int* __restrict__ cnts_t, int NC)
{
  int k = threadIdx.x;
  int run = 0;
  int* p = cnts_t + k * NC;
  for (int m = 0; m < NC; ++m) { int t = p[m]; p[m] = run; run += t; }
}

// ---- K3a: level-1 exclusive scan (16 chunks/group, in place) + group totals ----
__global__ __launch_bounds__(256) void k3a_scan_lo(float* __restrict__ sums, float* __restrict__ aux)
{
  int g   = blockIdx.x / 192;
  int col = (blockIdx.x % 192) * 256 + threadIdx.x;
  float run = 0.f;
  for (int m = g * 16; m < g * 16 + 16; ++m) {
    size_t idx = (size_t)m * (K * D) + col;
    float t = sums[idx]; sums[idx] = run; run += t;
  }
  aux[(size_t)g * (K * D) + col] = run;
}

// ---- K3b: scan group totals ----
__global__ __launch_bounds__(256) void k3b_scan_hi(float* __restrict__ aux)
{
  int col = blockIdx.x * 256 + threadIdx.x;
  float run = 0.f;
  for (int g = 0; g < 16; ++g) {
    size_t idx = (size_t)g * (K * D) + col;
    float t = aux[idx]; aux[idx] = run; run += t;
  }
}

// ---- K4: fused GEMMs + epilogue. 512 threads, 73 KB LDS -> 2 blocks/CU. ----
// 6 slabs of 128 cols; pv/bn2 computed during staging (shfl-reduce + 1 atomic);
// epilogue: wave0 builds 8 checkpoints (112 serial steps), 8 waves emit 16 rows.
#define LDV2 136  // bf16 row stride for 128-col tiles
#define LDD  132  // f32 dot LDS stride
__global__ __launch_bounds__(512, 4) void k4_v2(
    const unsigned short* __restrict__ Vb, const float* __restrict__ sums,
    const float* __restrict__ aux, const unsigned short* __restrict__ cavgb,
    const int* __restrict__ labels, const int* __restrict__ cnts_t,
    const float* __restrict__ cn2, float* __restrict__ out)
{
  __shared__ unsigned short smem[2 * 128 * LDV2];   // Vt | Bt; later f32 dot[128][LDD]
  __shared__ float pvL[128];
  __shared__ float bn2L[64];
  __shared__ int   labL[128];
  __shared__ float chk[8][64];
  unsigned short* Vt = smem;
  unsigned short* Bt = smem + 128 * LDV2;
  const int m = blockIdx.x;
  const int g = m >> 4;
  const int tid = threadIdx.x;
  const int w = tid >> 6, l = tid & 63;
  const int r31 = l & 31, kh = l >> 5;
  const int wr = w & 3;          // output row-tile (32 rows)
  const int wt = (w >> 2) * 2;   // output col-tile base

  if (tid < 128) { pvL[tid] = 0.f; labL[tid] = labels[m * 128 + tid]; }
  if (tid < 64) bn2L[tid] = 0.f;
  __syncthreads();

  f32x16 accP[2], accS[2];
  accP[0] = (f32x16){}; accP[1] = (f32x16){};
  accS[0] = (f32x16){}; accS[1] = (f32x16){};

  for (int s = 0; s < 6; ++s) {
    // ---- stage V + B' slab (128 rows x 128 cols each) ----
#pragma unroll
    for (int it = 0; it < 4; ++it) {
      int flat = it * 512 + tid;
      int row = flat >> 4, c = flat & 15;
      uint4 uv = *(const uint4*)(Vb + (size_t)(m * 128 + row) * D + s * 128 + c * 8);
      *(uint4*)(Vt + row * LDV2 + c * 8) = uv;
      {  // pv partial from bf16 (16 lanes per row)
        float sq = 0.f;
        unsigned ua[4] = {uv.x, uv.y, uv.z, uv.w};
#pragma unroll
        for (int q = 0; q < 4; ++q) {
          float lo = __uint_as_float(ua[q] << 16);
          float hi = __uint_as_float(ua[q] & 0xFFFF0000u);
          sq += lo * lo + hi * hi;
        }
        sq += __shfl_xor(sq, 1); sq += __shfl_xor(sq, 2);
        sq += __shfl_xor(sq, 4); sq += __shfl_xor(sq, 8);
        if ((l & 15) == 0) atomicAdd(&pvL[row], sq);
      }
      if (row < 64) {   // scanned base rows: f32 sums+aux, convert + bn2
        const float* sp = sums + ((size_t)m * K + row) * D + s * 128 + c * 8;
        const float* ap = aux + ((size_t)g * K + row) * D + s * 128 + c * 8;
        float4 b0 = a4(*(const float4*)sp, *(const float4*)ap);
        float4 b1 = a4(*(const float4*)(sp + 4), *(const float4*)(ap + 4));
        float sq = d4f(b0, b0) + d4f(b1, b1);
        sq += __shfl_xor(sq, 1); sq += __shfl_xor(sq, 2);
        sq += __shfl_xor(sq, 4); sq += __shfl_xor(sq, 8);
        if ((l & 15) == 0) atomicAdd(&bn2L[row], sq);
        uint4 u;
        u.x = (unsigned)f2bf(b0.x) | ((unsigned)f2bf(b0.y) << 16);
        u.y = (unsigned)f2bf(b0.z) | ((unsigned)f2bf(b0.w) << 16);
        u.z = (unsigned)f2bf(b1.x) | ((unsigned)f2bf(b1.y) << 16);
        u.w = (unsigned)f2bf(b1.z) | ((unsigned)f2bf(b1.w) << 16);
        *(uint4*)(Bt + row * LDV2 + c * 8) = u;
      } else {          // cavg rows: already bf16
        *(uint4*)(Bt + row * LDV2 + c * 8) =
            *(const uint4*)(cavgb + (size_t)(row - 64) * D + s * 128 + c * 8);
      }
    }
    __syncthreads();
    // ---- MFMA on this slab ----
#pragma unroll
    for (int kk = 0; kk < 8; ++kk) {
      bf16x8 av = *(const bf16x8*)(Vt + (32 * wr + r31) * LDV2 + kk * 16 + kh * 8);
#pragma unroll
      for (int ti = 0; ti < 2; ++ti) {
        int t = wt + ti;
        bf16x8 bB = *(const bf16x8*)(Bt + (32 * t + r31) * LDV2 + kk * 16 + kh * 8);
        accP[ti] = __builtin_amdgcn_mfma_f32_32x32x16_bf16(av, bB, accP[ti], 0, 0, 0);
        bf16x8 bV = *(const bf16x8*)(Vt + (32 * t + r31) * LDV2 + kk * 16 + kh * 8);
        accS[ti] = __builtin_amdgcn_mfma_f32_32x32x16_bf16(av, bV, accS[ti], 0, 0, 0);
      }
    }
    __syncthreads();
  }

  // ---- masked S -> bf16 into Vt region; one-hot Mt into Bt region ----
#pragma unroll
  for (int ti = 0; ti < 2; ++ti)
#pragma unroll
    for (int q = 0; q < 16; ++q) {
      int i = 32 * wr + (q & 3) + 8 * (q >> 2) + 4 * kh;
      int j = 32 * (wt + ti) + r31;
      Vt[i * LDV2 + j] = (j < i) ? f2bf(accS[ti][q]) : (unsigned short)0;
    }
  {
    int j = tid & 127;
    int lab = labL[j];
    int kb = (tid >> 7) * 16;
#pragma unroll
    for (int kk = 0; kk < 16; ++kk) {
      int k = kb + kk;
      Bt[k * LDV2 + j] = (lab == k) ? (unsigned short)0x3F80 : (unsigned short)0;
    }
  }
  __syncthreads();

  // ---- corr = tril_strict(S) @ onehot, into accP (class cols, waves 0-3) ----
  if (w < 4) {
#pragma unroll
    for (int kk = 0; kk < 8; ++kk) {
      bf16x8 aS = *(const bf16x8*)(Vt + (32 * wr + r31) * LDV2 + kk * 16 + kh * 8);
#pragma unroll
      for (int ti = 0; ti < 2; ++ti) {
        bf16x8 bM = *(const bf16x8*)(Bt + (32 * ti + r31) * LDV2 + kk * 16 + kh * 8);
        accP[ti] = __builtin_amdgcn_mfma_f32_32x32x16_bf16(aS, bM, accP[ti], 0, 0, 0);
      }
    }
  }
  __syncthreads();

  // ---- dot matrix -> LDS (overwrites tiles) ----
  float* dotL = (float*)smem;
#pragma unroll
  for (int ti = 0; ti < 2; ++ti)
#pragma unroll
    for (int q = 0; q < 16; ++q) {
      int i = 32 * wr + (q & 3) + 8 * (q >> 2) + 4 * kh;
      int col = 32 * (wt + ti) + r31;
      dotL[i * LDD + col] = accP[ti][q];
    }
  __syncthreads();

  // ---- wave 0: norm-recurrence checkpoints every 16 rows ----
  if (w == 0) {
    int k = l;
    bool seen = cnts_t[k * NCF + m] > 0;
    float n = seen ? bn2L[k] : 0.f;
    for (int seg = 0; seg < 8; ++seg) {
      chk[seg][k] = seen ? n : -1.f;
      if (seg == 7) break;
      for (int j = seg * 16; j < seg * 16 + 16; ++j) {
        float dS = dotL[j * LDD + k];
        float pvj = pvL[j];
        if (labL[j] == k) {
          n = seen ? (n + 2.f * dS + pvj) : pvj;
          seen = true;
        }
      }
    }
  }
  __syncthreads();

  // ---- all 8 waves: emit 16-row segment from checkpoint ----
  {
    int k = l;
    float st = chk[w][k];
    bool seen = st >= 0.f;
    float n = seen ? st : 0.f;
    float cnk = cn2[k];
    int jb = w * 16;
    for (int j = jb; j < jb + 16; ++j) {
      float dS = dotL[j * LDD + k];
      float dC = dotL[j * LDD + 64 + k];
      float pvj = pvL[j];
      int lab = labL[j];
      float val = seen ? dS : dC;
      float nn  = seen ? n : cnk;
      out[(size_t)(m * 128 + j) * K + k] = val * rsqrtf(fmaxf(nn * pvj, 1e-30f));
      if (lab == k) {
        n = seen ? (n + 2.f * dS + pvj) : pvj;
        seen = true;
      }
    }
  }
}

// =====================================================================
// FALLBACK PATH — round-1 pipeline, verbatim (known-correct)
// =====================================================================
__global__ __launch_bounds__(256) void ph1_chunk_sums(
    const float* __restrict__ inputs, const int* __restrict__ labels,
    float* __restrict__ sums, int* __restrict__ cnts, int NC, int C)
{
  __shared__ float acc[4 * K * 64];
  __shared__ int   hist[4 * K];
  const int bi    = blockIdx.x;
  const int chunk = bi / 12, slice = bi % 12;
  const int w = threadIdx.x >> 6, l = threadIdx.x & 63;

  for (int e = threadIdx.x; e < 4 * K * 64; e += 256) acc[e] = 0.f;
  hist[threadIdx.x] = 0;
  __syncthreads();

  const int C4 = C >> 2;
  const long long rbase = (long long)chunk * C + (long long)w * C4;
  float* accw = acc + w * (K * 64);
  for (int j = 0; j < C4; ++j) {
    long long r = rbase + j;
    int lab = labels[r];
    float v = inputs[r * D + slice * 64 + l];
    accw[lab * 64 + l] += v;
    if (slice == 0 && l == 0) hist[w * K + lab]++;
  }
  __syncthreads();

  float* sp = sums + (long long)chunk * (K * D) + slice * 64;
  for (int e = threadIdx.x; e < K * 64; e += 256) {
    int k = e >> 6, dl = e & 63;
    float s = acc[0*K*64 + e] + acc[1*K*64 + e] + acc[2*K*64 + e] + acc[3*K*64 + e];
    sp[k * D + dl] = s;
  }
  if (slice == 0 && threadIdx.x < K) {
    cnts[chunk * K + threadIdx.x] =
        hist[0*K + threadIdx.x] + hist[1*K + threadIdx.x] +
        hist[2*K + threadIdx.x] + hist[3*K + threadIdx.x];
  }
}

__global__ __launch_bounds__(256) void ph2a_scan_sums(float* __restrict__ sums, int NC)
{
  const int tid = blockIdx.x * 256 + threadIdx.x;
  float run = 0.f;
  for (int m = 0; m < NC; ++m) {
    long long idx = (long long)m * (K * D) + tid;
    float t = sums[idx];
    sums[idx] = run;
    run += t;
  }
}

__global__ void ph2b_scan_cnts(int* __restrict__ cnts, int NC)
{
  const int k = threadIdx.x;
  int run = 0;
  for (int m = 0; m < NC; ++m) {
    int t = cnts[m * K + k];
    cnts[m * K + k] = run;
    run += t;
  }
}

__global__ __launch_bounds__(256, 4) void ph3_scan(
    const float* __restrict__ inputs, const int* __restrict__ labels,
    const float* __restrict__ cavg, const float* __restrict__ base,
    const int* __restrict__ cnts, float* __restrict__ out, int NC, int C)
{
  const int bi = blockIdx.x;
  int chunk, quad;
  if (NC >= 8) {
    int xcd = bi & 7, slot = bi >> 3;
    chunk = xcd * (NC >> 3) + (slot >> 2);
    quad  = slot & 3;
  } else {
    chunk = bi >> 2; quad = bi & 3;
  }
  const int w = threadIdx.x >> 6, l = threadIdx.x & 63;
  const int k0 = (quad * 4 + w) * 4;

  const int cb = chunk * K + k0;
  bool vg0 = (cnts[cb+0] == 0), vg1 = (cnts[cb+1] == 0);
  bool vg2 = (cnts[cb+2] == 0), vg3 = (cnts[cb+3] == 0);

  const float4* bp = (const float4*)base + (long long)chunk * (K * D4);
  const float4* cp = (const float4*)cavg;

  float4 A0[3], A1[3], A2[3], A3[3];
#pragma unroll
  for (int t = 0; t < 3; ++t) {
    int o = t * 64 + l;
    A0[t] = vg0 ? cp[(k0+0)*D4 + o] : bp[(k0+0)*D4 + o];
    A1[t] = vg1 ? cp[(k0+1)*D4 + o] : bp[(k0+1)*D4 + o];
    A2[t] = vg2 ? cp[(k0+2)*D4 + o] : bp[(k0+2)*D4 + o];
    A3[t] = vg3 ? cp[(k0+3)*D4 + o] : bp[(k0+3)*D4 + o];
  }
  float n0 = 0.f, n1 = 0.f, n2 = 0.f, n3 = 0.f;
#pragma unroll
  for (int t = 0; t < 3; ++t) {
    n0 += d4f(A0[t], A0[t]); n1 += d4f(A1[t], A1[t]);
    n2 += d4f(A2[t], A2[t]); n3 += d4f(A3[t], A3[t]);
  }
#pragma unroll
  for (int m = 1; m <= 32; m <<= 1) {
    n0 += __shfl_xor(n0, m); n1 += __shfl_xor(n1, m);
    n2 += __shfl_xor(n2, m); n3 += __shfl_xor(n3, m);
  }

  const long long ibase = (long long)chunk * C;
  for (int j = 0; j < C; ++j) {
    const long long i = ibase + j;
    const int lab = labels[i];
    const float4* vp = (const float4*)inputs + i * D4;
    float4 v0 = vp[l], v1 = vp[64 + l], v2 = vp[128 + l];

    float p0 = d4f(A0[0], v0) + d4f(A0[1], v1) + d4f(A0[2], v2);
    float p1 = d4f(A1[0], v0) + d4f(A1[1], v1) + d4f(A1[2], v2);
    float p2 = d4f(A2[0], v0) + d4f(A2[1], v1) + d4f(A2[2], v2);
    float p3 = d4f(A3[0], v0) + d4f(A3[1], v1) + d4f(A3[2], v2);
    float pv = d4f(v0, v0) + d4f(v1, v1) + d4f(v2, v2);
#pragma unroll
    for (int m = 1; m <= 32; m <<= 1) {
      p0 += __shfl_xor(p0, m); p1 += __shfl_xor(p1, m);
      p2 += __shfl_xor(p2, m); p3 += __shfl_xor(p3, m);
      pv += __shfl_xor(pv, m);
    }
    if (l < 4) {
      float ps = (l == 0) ? p0 : (l == 1) ? p1 : (l == 2) ? p2 : p3;
      float ns = (l == 0) ? n0 : (l == 1) ? n1 : (l == 2) ? n2 : n3;
      out[i * K + k0 + l] = ps * rsqrtf(fmaxf(ns * pv, 1e-30f));
    }
#define UPD(idx) do { \
      if (vg##idx) { A##idx[0]=v0; A##idx[1]=v1; A##idx[2]=v2; n##idx = pv; vg##idx = false; } \
      else { A##idx[0]=a4(A##idx[0],v0); A##idx[1]=a4(A##idx[1],v1); A##idx[2]=a4(A##idx[2],v2); \
             n##idx += 2.f * p##idx + pv; } } while (0)
    if      (lab == k0 + 0) UPD(0);
    else if (lab == k0 + 1) UPD(1);
    else if (lab == k0 + 2) UPD(2);
    else if (lab == k0 + 3) UPD(3);
#undef UPD
  }
}

// =====================================================================
extern "C" void kernel_launch(void* const* d_in, const int* in_sizes, int n_in,
                              void* d_out, int out_size, void* d_ws, size_t ws_size,
                              hipStream_t stream)
{
  const float* inputs = (const float*)d_in[0];
  const int*   labels = (const int*)d_in[1];
  const float* cavg   = (const float*)d_in[2];
  float* out = (float*)d_out;
  const int N = in_sizes[1];

  const size_t szVb    = (size_t)32768 * D * 2;   // 50.3 MB
  const size_t szSums  = (size_t)NCF * K * D * 4; // 50.3 MB
  const size_t szAux   = (size_t)16 * K * D * 4;  // 3.1 MB
  const size_t szCnt   = (size_t)K * NCF * 4;
  const size_t szCavgb = (size_t)K * D * 2;
  const size_t szCn2   = (size_t)K * 4;
  size_t need = szVb + szSums + szAux + szCnt + szCavgb + szCn2 + 8 * 256;

  if (N == 32768 && in_sizes[2] == K * D && ws_size >= need) {
    char* p = (char*)d_ws;
    auto take = [&](size_t b) { char* r = p; p += (b + 255) & ~(size_t)255; return r; };
    unsigned short* Vb    = (unsigned short*)take(szVb);
    float*          sums  = (float*)take(szSums);
    float*          aux   = (float*)take(szAux);
    int*            cnts  = (int*)take(szCnt);
    unsigned short* cavgb = (unsigned short*)take(szCavgb);
    float*          cn2   = (float*)take(szCn2);

    hipLaunchKernelGGL(k1c, dim3(16), dim3(256), 0, stream, cavg, cavgb, cn2);
    hipLaunchKernelGGL(k2_atomic, dim3(NCF * 3), dim3(256), 0, stream,
                       inputs, labels, Vb, sums, cnts);
    hipLaunchKernelGGL(k2b_scan_cnts, dim3(1), dim3(K), 0, stream, cnts, NCF);
    hipLaunchKernelGGL(k3a_scan_lo, dim3(16 * 192), dim3(256), 0, stream, sums, aux);
    hipLaunchKernelGGL(k3b_scan_hi, dim3(192), dim3(256), 0, stream, aux);
    hipLaunchKernelGGL(k4_v2, dim3(NCF), dim3(512), 0, stream,
                       Vb, sums, aux, cavgb, labels, cnts, cn2, out);
    return;
  }

  // ---------------- fallback: round-1 pipeline ----------------
  int NC = 256;
  while (NC > 1) {
    size_t nd = (size_t)NC * K * D * 4 + (size_t)NC * K * 4;
    if (nd <= ws_size && (N % (NC * 4)) == 0) break;
    NC >>= 1;
  }
  const int C = N / NC;
  float* d_sums = (float*)d_ws;
  int*   d_cnts = (int*)((char*)d_ws + (size_t)NC * K * D * 4);

  hipLaunchKernelGGL(ph1_chunk_sums, dim3(NC * 12), dim3(256), 0, stream,
                     inputs, labels, d_sums, d_cnts, NC, C);
  hipLaunchKernelGGL(ph2a_scan_sums, dim3((K * D) / 256), dim3(256), 0, stream,
                     d_sums, NC);
  hipLaunchKernelGGL(ph2b_scan_cnts, dim3(1), dim3(64), 0, stream,
                     d_cnts, NC);
  hipLaunchKernelGGL(ph3_scan, dim3(NC * 4), dim3(256), 0, stream,
                     inputs, labels, cavg, d_sums, d_cnts, out, NC, C);
}

// Round 6
// 145.124 us; speedup vs baseline: 1.8851x; 1.8851x over previous
//
#include <hip/hip_runtime.h>
#include <cstddef>

#define K 64
#define D 768
#define D4 192   // D/4

__device__ __forceinline__ float d4f(float4 a, float4 b) {
  return a.x*b.x + a.y*b.y + a.z*b.z + a.w*b.w;
}
__device__ __forceinline__ float4 a4(float4 a, float4 b) {
  return make_float4(a.x+b.x, a.y+b.y, a.z+b.z, a.w+b.w);
}
__device__ __forceinline__ unsigned short f2bf(float x) {
  unsigned int u = __float_as_uint(x);
  unsigned int r = (u + 0x7FFFu + ((u >> 16) & 1u)) >> 16;
  return (unsigned short)r;
}

typedef __attribute__((ext_vector_type(8)))  short bf16x8;
typedef __attribute__((ext_vector_type(16))) float f32x16;

// =====================================================================
// FAST PATH (N=32768, NC=256, C=128)
// =====================================================================
#define NCF 256
#define CF  128
#define NF  32768

// ---- K1c: cast cavg to bf16 + exact ||row||^2 ----
__global__ __launch_bounds__(256) void k1c(
    const float* __restrict__ cavg, unsigned short* __restrict__ cavgb,
    float* __restrict__ cn2)
{
  int wave = blockIdx.x * 4 + (threadIdx.x >> 6);
  int l = threadIdx.x & 63;
  if (wave >= K) return;
  const float* src = cavg + (size_t)wave * D;
  unsigned short* dst = cavgb + (size_t)wave * D;
  float sq = 0.f;
#pragma unroll
  for (int t = 0; t < 3; ++t) {
    float4 v = ((const float4*)src)[t * 64 + l];
    sq += v.x*v.x + v.y*v.y + v.z*v.z + v.w*v.w;
    ushort4 o; o.x = f2bf(v.x); o.y = f2bf(v.y); o.z = f2bf(v.z); o.w = f2bf(v.w);
    ((ushort4*)dst)[t * 64 + l] = o;
  }
#pragma unroll
  for (int m = 1; m <= 32; m <<= 1) sq += __shfl_xor(sq, m);
  if (l == 0) cn2[wave] = sq;
}

// ---- K2v3: fused cast + per-chunk sums GEMM, 3 blocks/chunk (2 slabs each) ----
// Stages f32 inputs (coalesced row-major), converts in-register to Vt (LDS) +
// Vb (global); sums = Mt[64x128] @ V[128xD] via validated MFMA core;
// pv partials per slab-group -> pvpart[g][i].
#define LDT2 132  // Vt row stride (bf16 elems)
#define LDM  136  // Mt row stride
__global__ __launch_bounds__(256) void k2_v3(
    const float* __restrict__ inputs, const int* __restrict__ labels,
    unsigned short* __restrict__ Vb, float* __restrict__ pvpart,
    float* __restrict__ sums, int* __restrict__ cnts_t)
{
  __shared__ unsigned short Vt[128 * LDT2];   // 33792 B
  __shared__ unsigned short Mt[64 * LDM];     // 17408 B
  __shared__ float pvrow[128];
  const int bi = blockIdx.x;
  const int m = bi / 3, g = bi % 3;
  const int tid = threadIdx.x;
  const int w = tid >> 6, l = tid & 63;
  const int r31 = l & 31, kh = l >> 5;

  for (int e = tid; e < 64 * LDM / 2; e += 256) ((unsigned int*)Mt)[e] = 0u;
  if (tid < 128) pvrow[tid] = 0.f;
  __syncthreads();
  if (tid < 128) Mt[labels[m * 128 + tid] * LDM + tid] = 0x3F80;
  __syncthreads();
  if (g == 0 && tid < 64) {
    int c = 0;
    for (int j = 0; j < 128; ++j) c += (Mt[tid * LDM + j] != 0);
    cnts_t[tid * NCF + m] = c;
  }

  for (int sl = 0; sl < 2; ++sl) {
    const int kd = g * 2 + sl;
    f32x16 acc0 = (f32x16){}, acc1 = (f32x16){};
    __syncthreads();
    // stage: f32 -> bf16 into Vt + Vb, pv partials (32 threads per row-segment)
#pragma unroll 4
    for (int it = 0; it < 16; ++it) {
      int flat = it * 256 + tid;
      int row = flat >> 5, c = flat & 31;
      float4 f = *(const float4*)(inputs + (size_t)(m * 128 + row) * D + kd * 128 + c * 4);
      float sq = d4f(f, f);
      sq += __shfl_xor(sq, 1); sq += __shfl_xor(sq, 2); sq += __shfl_xor(sq, 4);
      sq += __shfl_xor(sq, 8); sq += __shfl_xor(sq, 16);
      if ((tid & 31) == 0) pvrow[row] += sq;
      ushort4 o; o.x = f2bf(f.x); o.y = f2bf(f.y); o.z = f2bf(f.z); o.w = f2bf(f.w);
      *(ushort4*)(Vt + row * LDT2 + c * 4) = o;
      *(ushort4*)(Vb + (size_t)(m * 128 + row) * D + kd * 128 + c * 4) = o;
    }
    __syncthreads();
#pragma unroll
    for (int kk = 0; kk < 8; ++kk) {
      bf16x8 a0 = *(const bf16x8*)(Mt + (r31) * LDM + kk * 16 + kh * 8);
      bf16x8 a1 = *(const bf16x8*)(Mt + (32 + r31) * LDM + kk * 16 + kh * 8);
      bf16x8 b;
#pragma unroll
      for (int r = 0; r < 8; ++r)
        b[r] = *(const short*)(Vt + (kk * 16 + kh * 8 + r) * LDT2 + w * 32 + r31);
      acc0 = __builtin_amdgcn_mfma_f32_32x32x16_bf16(a0, b, acc0, 0, 0, 0);
      acc1 = __builtin_amdgcn_mfma_f32_32x32x16_bf16(a1, b, acc1, 0, 0, 0);
    }
    float* sp = sums + (size_t)m * (K * D) + kd * 128;
#pragma unroll
    for (int q = 0; q < 16; ++q) {
      int kc = (q & 3) + 8 * (q >> 2) + 4 * kh;
      sp[(size_t)kc * D + w * 32 + r31]        = acc0[q];
      sp[(size_t)(32 + kc) * D + w * 32 + r31] = acc1[q];
    }
  }
  __syncthreads();
  if (tid < 128) pvpart[(size_t)g * NF + m * 128 + tid] = pvrow[tid];
}

// ---- K2b: exclusive scan of transposed counts ----
__global__ void k2b_scan_cnts(int* __restrict__ cnts_t, int NC)
{
  int k = threadIdx.x;
  int run = 0;
  int* p = cnts_t + k * NC;
  for (int m = 0; m < NC; ++m) { int t = p[m]; p[m] = run; run += t; }
}

// ---- K3a: level-1 exclusive scan (16 chunks/group, in place) + group totals ----
__global__ __launch_bounds__(256) void k3a_scan_lo(float* __restrict__ sums, float* __restrict__ aux)
{
  int g   = blockIdx.x / 192;
  int col = (blockIdx.x % 192) * 256 + threadIdx.x;
  float run = 0.f;
  for (int m = g * 16; m < g * 16 + 16; ++m) {
    size_t idx = (size_t)m * (K * D) + col;
    float t = sums[idx]; sums[idx] = run; run += t;
  }
  aux[(size_t)g * (K * D) + col] = run;
}

// ---- K3b: scan group totals ----
__global__ __launch_bounds__(256) void k3b_scan_hi(float* __restrict__ aux)
{
  int col = blockIdx.x * 256 + threadIdx.x;
  float run = 0.f;
  for (int g = 0; g < 16; ++g) {
    size_t idx = (size_t)g * (K * D) + col;
    float t = aux[idx]; aux[idx] = run; run += t;
  }
}

// ---- K4v3: fused GEMMs + epilogue; V-tile register prefetch (T14). ----
#define LDV2 136  // bf16 row stride for 128-col tiles
#define LDD  132  // f32 dot LDS stride
__global__ __launch_bounds__(512, 4) void k4_v3(
    const unsigned short* __restrict__ Vb, const float* __restrict__ sums,
    const float* __restrict__ aux, const unsigned short* __restrict__ cavgb,
    const int* __restrict__ labels, const float* __restrict__ pvpart,
    const int* __restrict__ cnts_t, const float* __restrict__ cn2,
    float* __restrict__ out)
{
  __shared__ unsigned short smem[2 * 128 * LDV2];   // Vt | Bt; later f32 dot[128][LDD]
  __shared__ float pvL[128];
  __shared__ float bn2L[64];
  __shared__ int   labL[128];
  __shared__ float chk[8][64];
  unsigned short* Vt = smem;
  unsigned short* Bt = smem + 128 * LDV2;
  const int m = blockIdx.x;
  const int g = m >> 4;
  const int tid = threadIdx.x;
  const int w = tid >> 6, l = tid & 63;
  const int r31 = l & 31, kh = l >> 5;
  const int wr = w & 3;          // output row-tile (32 rows)
  const int wt = (w >> 2) * 2;   // output col-tile base

  if (tid < 128) {
    int i = m * 128 + tid;
    pvL[tid] = pvpart[i] + pvpart[NF + i] + pvpart[2 * NF + i];
    labL[tid] = labels[i];
  }
  if (tid < 64) bn2L[tid] = 0.f;
  __syncthreads();

  f32x16 accP[2], accS[2];
  accP[0] = (f32x16){}; accP[1] = (f32x16){};
  accS[0] = (f32x16){}; accS[1] = (f32x16){};

  // V-tile prefetch registers (slab 0)
  uint4 vreg[4];
#pragma unroll
  for (int it = 0; it < 4; ++it) {
    int flat = it * 512 + tid;
    int row = flat >> 4, c = flat & 15;
    vreg[it] = *(const uint4*)(Vb + (size_t)(m * 128 + row) * D + c * 8);
  }

  for (int s = 0; s < 6; ++s) {
    // ---- write phase: V regs -> LDS; stage B' (sums+aux / cavgb) ----
#pragma unroll
    for (int it = 0; it < 4; ++it) {
      int flat = it * 512 + tid;
      int row = flat >> 4, c = flat & 15;
      *(uint4*)(Vt + row * LDV2 + c * 8) = vreg[it];
      if (row < 64) {   // scanned base rows: f32 sums+aux, convert + bn2
        const float* sp = sums + ((size_t)m * K + row) * D + s * 128 + c * 8;
        const float* ap = aux + ((size_t)g * K + row) * D + s * 128 + c * 8;
        float4 b0 = a4(*(const float4*)sp, *(const float4*)ap);
        float4 b1 = a4(*(const float4*)(sp + 4), *(const float4*)(ap + 4));
        float sq = d4f(b0, b0) + d4f(b1, b1);
        sq += __shfl_xor(sq, 1); sq += __shfl_xor(sq, 2);
        sq += __shfl_xor(sq, 4); sq += __shfl_xor(sq, 8);
        if ((l & 15) == 0) atomicAdd(&bn2L[row], sq);
        uint4 u;
        u.x = (unsigned)f2bf(b0.x) | ((unsigned)f2bf(b0.y) << 16);
        u.y = (unsigned)f2bf(b0.z) | ((unsigned)f2bf(b0.w) << 16);
        u.z = (unsigned)f2bf(b1.x) | ((unsigned)f2bf(b1.y) << 16);
        u.w = (unsigned)f2bf(b1.z) | ((unsigned)f2bf(b1.w) << 16);
        *(uint4*)(Bt + row * LDV2 + c * 8) = u;
      } else {          // cavg rows: already bf16
        *(uint4*)(Bt + row * LDV2 + c * 8) =
            *(const uint4*)(cavgb + (size_t)(row - 64) * D + s * 128 + c * 8);
      }
    }
    __syncthreads();
    // ---- issue next-slab V loads (latency hides under MFMA) ----
    if (s < 5) {
#pragma unroll
      for (int it = 0; it < 4; ++it) {
        int flat = it * 512 + tid;
        int row = flat >> 4, c = flat & 15;
        vreg[it] = *(const uint4*)(Vb + (size_t)(m * 128 + row) * D + (s + 1) * 128 + c * 8);
      }
    }
    // ---- MFMA on this slab ----
#pragma unroll
    for (int kk = 0; kk < 8; ++kk) {
      bf16x8 av = *(const bf16x8*)(Vt + (32 * wr + r31) * LDV2 + kk * 16 + kh * 8);
#pragma unroll
      for (int ti = 0; ti < 2; ++ti) {
        int t = wt + ti;
        bf16x8 bB = *(const bf16x8*)(Bt + (32 * t + r31) * LDV2 + kk * 16 + kh * 8);
        accP[ti] = __builtin_amdgcn_mfma_f32_32x32x16_bf16(av, bB, accP[ti], 0, 0, 0);
        bf16x8 bV = *(const bf16x8*)(Vt + (32 * t + r31) * LDV2 + kk * 16 + kh * 8);
        accS[ti] = __builtin_amdgcn_mfma_f32_32x32x16_bf16(av, bV, accS[ti], 0, 0, 0);
      }
    }
    __syncthreads();
  }

  // ---- masked S -> bf16 into Vt region; one-hot Mt into Bt region ----
#pragma unroll
  for (int ti = 0; ti < 2; ++ti)
#pragma unroll
    for (int q = 0; q < 16; ++q) {
      int i = 32 * wr + (q & 3) + 8 * (q >> 2) + 4 * kh;
      int j = 32 * (wt + ti) + r31;
      Vt[i * LDV2 + j] = (j < i) ? f2bf(accS[ti][q]) : (unsigned short)0;
    }
  {
    int j = tid & 127;
    int lab = labL[j];
    int kb = (tid >> 7) * 16;
#pragma unroll
    for (int kk = 0; kk < 16; ++kk) {
      int k = kb + kk;
      Bt[k * LDV2 + j] = (lab == k) ? (unsigned short)0x3F80 : (unsigned short)0;
    }
  }
  __syncthreads();

  // ---- corr = tril_strict(S) @ onehot, into accP (class cols, waves 0-3) ----
  if (w < 4) {
#pragma unroll
    for (int kk = 0; kk < 8; ++kk) {
      bf16x8 aS = *(const bf16x8*)(Vt + (32 * wr + r31) * LDV2 + kk * 16 + kh * 8);
#pragma unroll
      for (int ti = 0; ti < 2; ++ti) {
        bf16x8 bM = *(const bf16x8*)(Bt + (32 * ti + r31) * LDV2 + kk * 16 + kh * 8);
        accP[ti] = __builtin_amdgcn_mfma_f32_32x32x16_bf16(aS, bM, accP[ti], 0, 0, 0);
      }
    }
  }
  __syncthreads();

  // ---- dot matrix -> LDS (overwrites tiles) ----
  float* dotL = (float*)smem;
#pragma unroll
  for (int ti = 0; ti < 2; ++ti)
#pragma unroll
    for (int q = 0; q < 16; ++q) {
      int i = 32 * wr + (q & 3) + 8 * (q >> 2) + 4 * kh;
      int col = 32 * (wt + ti) + r31;
      dotL[i * LDD + col] = accP[ti][q];
    }
  __syncthreads();

  // ---- wave 0: norm-recurrence checkpoints every 16 rows ----
  if (w == 0) {
    int k = l;
    bool seen = cnts_t[k * NCF + m] > 0;
    float n = seen ? bn2L[k] : 0.f;
    for (int seg = 0; seg < 8; ++seg) {
      chk[seg][k] = seen ? n : -1.f;
      if (seg == 7) break;
      for (int j = seg * 16; j < seg * 16 + 16; ++j) {
        float dS = dotL[j * LDD + k];
        float pvj = pvL[j];
        if (labL[j] == k) {
          n = seen ? (n + 2.f * dS + pvj) : pvj;
          seen = true;
        }
      }
    }
  }
  __syncthreads();

  // ---- all 8 waves: emit 16-row segment from checkpoint ----
  {
    int k = l;
    float st = chk[w][k];
    bool seen = st >= 0.f;
    float n = seen ? st : 0.f;
    float cnk = cn2[k];
    int jb = w * 16;
    for (int j = jb; j < jb + 16; ++j) {
      float dS = dotL[j * LDD + k];
      float dC = dotL[j * LDD + 64 + k];
      float pvj = pvL[j];
      int lab = labL[j];
      float val = seen ? dS : dC;
      float nn  = seen ? n : cnk;
      out[(size_t)(m * 128 + j) * K + k] = val * rsqrtf(fmaxf(nn * pvj, 1e-30f));
      if (lab == k) {
        n = seen ? (n + 2.f * dS + pvj) : pvj;
        seen = true;
      }
    }
  }
}

// =====================================================================
// FALLBACK PATH — round-1 pipeline, verbatim (known-correct)
// =====================================================================
__global__ __launch_bounds__(256) void ph1_chunk_sums(
    const float* __restrict__ inputs, const int* __restrict__ labels,
    float* __restrict__ sums, int* __restrict__ cnts, int NC, int C)
{
  __shared__ float acc[4 * K * 64];
  __shared__ int   hist[4 * K];
  const int bi    = blockIdx.x;
  const int chunk = bi / 12, slice = bi % 12;
  const int w = threadIdx.x >> 6, l = threadIdx.x & 63;

  for (int e = threadIdx.x; e < 4 * K * 64; e += 256) acc[e] = 0.f;
  hist[threadIdx.x] = 0;
  __syncthreads();

  const int C4 = C >> 2;
  const long long rbase = (long long)chunk * C + (long long)w * C4;
  float* accw = acc + w * (K * 64);
  for (int j = 0; j < C4; ++j) {
    long long r = rbase + j;
    int lab = labels[r];
    float v = inputs[r * D + slice * 64 + l];
    accw[lab * 64 + l] += v;
    if (slice == 0 && l == 0) hist[w * K + lab]++;
  }
  __syncthreads();

  float* sp = sums + (long long)chunk * (K * D) + slice * 64;
  for (int e = threadIdx.x; e < K * 64; e += 256) {
    int k = e >> 6, dl = e & 63;
    float s = acc[0*K*64 + e] + acc[1*K*64 + e] + acc[2*K*64 + e] + acc[3*K*64 + e];
    sp[k * D + dl] = s;
  }
  if (slice == 0 && threadIdx.x < K) {
    cnts[chunk * K + threadIdx.x] =
        hist[0*K + threadIdx.x] + hist[1*K + threadIdx.x] +
        hist[2*K + threadIdx.x] + hist[3*K + threadIdx.x];
  }
}

__global__ __launch_bounds__(256) void ph2a_scan_sums(float* __restrict__ sums, int NC)
{
  const int tid = blockIdx.x * 256 + threadIdx.x;
  float run = 0.f;
  for (int m = 0; m < NC; ++m) {
    long long idx = (long long)m * (K * D) + tid;
    float t = sums[idx];
    sums[idx] = run;
    run += t;
  }
}

__global__ void ph2b_scan_cnts(int* __restrict__ cnts, int NC)
{
  const int k = threadIdx.x;
  int run = 0;
  for (int m = 0; m < NC; ++m) {
    int t = cnts[m * K + k];
    cnts[m * K + k] = run;
    run += t;
  }
}

__global__ __launch_bounds__(256, 4) void ph3_scan(
    const float* __restrict__ inputs, const int* __restrict__ labels,
    const float* __restrict__ cavg, const float* __restrict__ base,
    const int* __restrict__ cnts, float* __restrict__ out, int NC, int C)
{
  const int bi = blockIdx.x;
  int chunk, quad;
  if (NC >= 8) {
    int xcd = bi & 7, slot = bi >> 3;
    chunk = xcd * (NC >> 3) + (slot >> 2);
    quad  = slot & 3;
  } else {
    chunk = bi >> 2; quad = bi & 3;
  }
  const int w = threadIdx.x >> 6, l = threadIdx.x & 63;
  const int k0 = (quad * 4 + w) * 4;

  const int cb = chunk * K + k0;
  bool vg0 = (cnts[cb+0] == 0), vg1 = (cnts[cb+1] == 0);
  bool vg2 = (cnts[cb+2] == 0), vg3 = (cnts[cb+3] == 0);

  const float4* bp = (const float4*)base + (long long)chunk * (K * D4);
  const float4* cp = (const float4*)cavg;

  float4 A0[3], A1[3], A2[3], A3[3];
#pragma unroll
  for (int t = 0; t < 3; ++t) {
    int o = t * 64 + l;
    A0[t] = vg0 ? cp[(k0+0)*D4 + o] : bp[(k0+0)*D4 + o];
    A1[t] = vg1 ? cp[(k0+1)*D4 + o] : bp[(k0+1)*D4 + o];
    A2[t] = vg2 ? cp[(k0+2)*D4 + o] : bp[(k0+2)*D4 + o];
    A3[t] = vg3 ? cp[(k0+3)*D4 + o] : bp[(k0+3)*D4 + o];
  }
  float n0 = 0.f, n1 = 0.f, n2 = 0.f, n3 = 0.f;
#pragma unroll
  for (int t = 0; t < 3; ++t) {
    n0 += d4f(A0[t], A0[t]); n1 += d4f(A1[t], A1[t]);
    n2 += d4f(A2[t], A2[t]); n3 += d4f(A3[t], A3[t]);
  }
#pragma unroll
  for (int m = 1; m <= 32; m <<= 1) {
    n0 += __shfl_xor(n0, m); n1 += __shfl_xor(n1, m);
    n2 += __shfl_xor(n2, m); n3 += __shfl_xor(n3, m);
  }

  const long long ibase = (long long)chunk * C;
  for (int j = 0; j < C; ++j) {
    const long long i = ibase + j;
    const int lab = labels[i];
    const float4* vp = (const float4*)inputs + i * D4;
    float4 v0 = vp[l], v1 = vp[64 + l], v2 = vp[128 + l];

    float p0 = d4f(A0[0], v0) + d4f(A0[1], v1) + d4f(A0[2], v2);
    float p1 = d4f(A1[0], v0) + d4f(A1[1], v1) + d4f(A1[2], v2);
    float p2 = d4f(A2[0], v0) + d4f(A2[1], v1) + d4f(A2[2], v2);
    float p3 = d4f(A3[0], v0) + d4f(A3[1], v1) + d4f(A3[2], v2);
    float pv = d4f(v0, v0) + d4f(v1, v1) + d4f(v2, v2);
#pragma unroll
    for (int m = 1; m <= 32; m <<= 1) {
      p0 += __shfl_xor(p0, m); p1 += __shfl_xor(p1, m);
      p2 += __shfl_xor(p2, m); p3 += __shfl_xor(p3, m);
      pv += __shfl_xor(pv, m);
    }
    if (l < 4) {
      float ps = (l == 0) ? p0 : (l == 1) ? p1 : (l == 2) ? p2 : p3;
      float ns = (l == 0) ? n0 : (l == 1) ? n1 : (l == 2) ? n2 : n3;
      out[i * K + k0 + l] = ps * rsqrtf(fmaxf(ns * pv, 1e-30f));
    }
#define UPD(idx) do { \
      if (vg##idx) { A##idx[0]=v0; A##idx[1]=v1; A##idx[2]=v2; n##idx = pv; vg##idx = false; } \
      else { A##idx[0]=a4(A##idx[0],v0); A##idx[1]=a4(A##idx[1],v1); A##idx[2]=a4(A##idx[2],v2); \
             n##idx += 2.f * p##idx + pv; } } while (0)
    if      (lab == k0 + 0) UPD(0);
    else if (lab == k0 + 1) UPD(1);
    else if (lab == k0 + 2) UPD(2);
    else if (lab == k0 + 3) UPD(3);
#undef UPD
  }
}

// =====================================================================
extern "C" void kernel_launch(void* const* d_in, const int* in_sizes, int n_in,
                              void* d_out, int out_size, void* d_ws, size_t ws_size,
                              hipStream_t stream)
{
  const float* inputs = (const float*)d_in[0];
  const int*   labels = (const int*)d_in[1];
  const float* cavg   = (const float*)d_in[2];
  float* out = (float*)d_out;
  const int N = in_sizes[1];

  const size_t szVb    = (size_t)NF * D * 2;      // 50.3 MB
  const size_t szSums  = (size_t)NCF * K * D * 4; // 50.3 MB
  const size_t szAux   = (size_t)16 * K * D * 4;  // 3.1 MB
  const size_t szPv    = (size_t)3 * NF * 4;      // 393 KB (3 partials)
  const size_t szCnt   = (size_t)K * NCF * 4;
  const size_t szCavgb = (size_t)K * D * 2;
  const size_t szCn2   = (size_t)K * 4;
  size_t need = szVb + szSums + szAux + szPv + szCnt + szCavgb + szCn2 + 8 * 256;

  if (N == NF && in_sizes[2] == K * D && ws_size >= need) {
    char* p = (char*)d_ws;
    auto take = [&](size_t b) { char* r = p; p += (b + 255) & ~(size_t)255; return r; };
    unsigned short* Vb    = (unsigned short*)take(szVb);
    float*          sums  = (float*)take(szSums);
    float*          aux   = (float*)take(szAux);
    float*          pvp   = (float*)take(szPv);
    int*            cnts  = (int*)take(szCnt);
    unsigned short* cavgb = (unsigned short*)take(szCavgb);
    float*          cn2   = (float*)take(szCn2);

    hipLaunchKernelGGL(k1c, dim3(16), dim3(256), 0, stream, cavg, cavgb, cn2);
    hipLaunchKernelGGL(k2_v3, dim3(NCF * 3), dim3(256), 0, stream,
                       inputs, labels, Vb, pvp, sums, cnts);
    hipLaunchKernelGGL(k2b_scan_cnts, dim3(1), dim3(K), 0, stream, cnts, NCF);
    hipLaunchKernelGGL(k3a_scan_lo, dim3(16 * 192), dim3(256), 0, stream, sums, aux);
    hipLaunchKernelGGL(k3b_scan_hi, dim3(192), dim3(256), 0, stream, aux);
    hipLaunchKernelGGL(k4_v3, dim3(NCF), dim3(512), 0, stream,
                       Vb, sums, aux, cavgb, labels, pvp, cnts, cn2, out);
    return;
  }

  // ---------------- fallback: round-1 pipeline ----------------
  int NC = 256;
  while (NC > 1) {
    size_t nd = (size_t)NC * K * D * 4 + (size_t)NC * K * 4;
    if (nd <= ws_size && (N % (NC * 4)) == 0) break;
    NC >>= 1;
  }
  const int C = N / NC;
  float* d_sums = (float*)d_ws;
  int*   d_cnts = (int*)((char*)d_ws + (size_t)NC * K * D * 4);

  hipLaunchKernelGGL(ph1_chunk_sums, dim3(NC * 12), dim3(256), 0, stream,
                     inputs, labels, d_sums, d_cnts, NC, C);
  hipLaunchKernelGGL(ph2a_scan_sums, dim3((K * D) / 256), dim3(256), 0, stream,
                     d_sums, NC);
  hipLaunchKernelGGL(ph2b_scan_cnts, dim3(1), dim3(64), 0, stream,
                     d_cnts, NC);
  hipLaunchKernelGGL(ph3_scan, dim3(NC * 4), dim3(256), 0, stream,
                     inputs, labels, cavg, d_sums, d_cnts, out, NC, C);
}

// Round 7
// 136.119 us; speedup vs baseline: 2.0098x; 1.0662x over previous
//
#include <hip/hip_runtime.h>
#include <cstddef>

#define K 64
#define D 768
#define D4 192   // D/4

__device__ __forceinline__ float d4f(float4 a, float4 b) {
  return a.x*b.x + a.y*b.y + a.z*b.z + a.w*b.w;
}
__device__ __forceinline__ float4 a4(float4 a, float4 b) {
  return make_float4(a.x+b.x, a.y+b.y, a.z+b.z, a.w+b.w);
}
__device__ __forceinline__ unsigned short f2bf(float x) {
  unsigned int u = __float_as_uint(x);
  unsigned int r = (u + 0x7FFFu + ((u >> 16) & 1u)) >> 16;
  return (unsigned short)r;
}
__device__ __forceinline__ float bflo(unsigned u) { return __uint_as_float(u << 16); }
__device__ __forceinline__ float bfhi(unsigned u) { return __uint_as_float(u & 0xFFFF0000u); }

typedef __attribute__((ext_vector_type(8)))  short bf16x8;
typedef __attribute__((ext_vector_type(16))) float f32x16;

// =====================================================================
// FAST PATH (N=32768, NC=256, C=128)
// =====================================================================
#define NCF 256
#define CF  128
#define NF  32768

// ---- K1c: cast cavg to bf16 + exact ||row||^2 ----
__global__ __launch_bounds__(256) void k1c(
    const float* __restrict__ cavg, unsigned short* __restrict__ cavgb,
    float* __restrict__ cn2)
{
  int wave = blockIdx.x * 4 + (threadIdx.x >> 6);
  int l = threadIdx.x & 63;
  if (wave >= K) return;
  const float* src = cavg + (size_t)wave * D;
  unsigned short* dst = cavgb + (size_t)wave * D;
  float sq = 0.f;
#pragma unroll
  for (int t = 0; t < 3; ++t) {
    float4 v = ((const float4*)src)[t * 64 + l];
    sq += v.x*v.x + v.y*v.y + v.z*v.z + v.w*v.w;
    ushort4 o; o.x = f2bf(v.x); o.y = f2bf(v.y); o.z = f2bf(v.z); o.w = f2bf(v.w);
    ((ushort4*)dst)[t * 64 + l] = o;
  }
#pragma unroll
  for (int m = 1; m <= 32; m <<= 1) sq += __shfl_xor(sq, m);
  if (l == 0) cn2[wave] = sq;
}

// ---- K2v4: fused cast + per-chunk sums GEMM (bf16 sums out, no pv work) ----
#define LDT2 132  // Vt row stride (bf16 elems)
#define LDM  136  // Mt row stride
__global__ __launch_bounds__(256) void k2_v4(
    const float* __restrict__ inputs, const int* __restrict__ labels,
    unsigned short* __restrict__ Vb, unsigned short* __restrict__ sums,
    int* __restrict__ cnts_t)
{
  __shared__ unsigned short Vt[128 * LDT2];   // 33792 B
  __shared__ unsigned short Mt[64 * LDM];     // 17408 B
  const int bi = blockIdx.x;
  const int m = bi / 3, g = bi % 3;
  const int tid = threadIdx.x;
  const int w = tid >> 6, l = tid & 63;
  const int r31 = l & 31, kh = l >> 5;

  for (int e = tid; e < 64 * LDM / 2; e += 256) ((unsigned int*)Mt)[e] = 0u;
  __syncthreads();
  if (tid < 128) Mt[labels[m * 128 + tid] * LDM + tid] = 0x3F80;
  __syncthreads();
  if (g == 0 && tid < 64) {
    int c = 0;
    for (int j = 0; j < 128; ++j) c += (Mt[tid * LDM + j] != 0);
    cnts_t[tid * NCF + m] = c;
  }

  for (int sl = 0; sl < 2; ++sl) {
    const int kd = g * 2 + sl;
    f32x16 acc0 = (f32x16){}, acc1 = (f32x16){};
    __syncthreads();
    // stage: f32 -> bf16 into Vt + Vb (no reductions -> pure MLP)
#pragma unroll 4
    for (int it = 0; it < 16; ++it) {
      int flat = it * 256 + tid;
      int row = flat >> 5, c = flat & 31;
      float4 f = *(const float4*)(inputs + (size_t)(m * 128 + row) * D + kd * 128 + c * 4);
      ushort4 o; o.x = f2bf(f.x); o.y = f2bf(f.y); o.z = f2bf(f.z); o.w = f2bf(f.w);
      *(ushort4*)(Vt + row * LDT2 + c * 4) = o;
      *(ushort4*)(Vb + (size_t)(m * 128 + row) * D + kd * 128 + c * 4) = o;
    }
    __syncthreads();
#pragma unroll
    for (int kk = 0; kk < 8; ++kk) {
      bf16x8 a0 = *(const bf16x8*)(Mt + (r31) * LDM + kk * 16 + kh * 8);
      bf16x8 a1 = *(const bf16x8*)(Mt + (32 + r31) * LDM + kk * 16 + kh * 8);
      bf16x8 b;
#pragma unroll
      for (int r = 0; r < 8; ++r)
        b[r] = *(const short*)(Vt + (kk * 16 + kh * 8 + r) * LDT2 + w * 32 + r31);
      acc0 = __builtin_amdgcn_mfma_f32_32x32x16_bf16(a0, b, acc0, 0, 0, 0);
      acc1 = __builtin_amdgcn_mfma_f32_32x32x16_bf16(a1, b, acc1, 0, 0, 0);
    }
    unsigned short* sp = sums + (size_t)m * (K * D) + kd * 128;
#pragma unroll
    for (int q = 0; q < 16; ++q) {
      int kc = (q & 3) + 8 * (q >> 2) + 4 * kh;
      sp[(size_t)kc * D + w * 32 + r31]        = f2bf(acc0[q]);
      sp[(size_t)(32 + kc) * D + w * 32 + r31] = f2bf(acc1[q]);
    }
  }
}

// ---- K2b: exclusive scan of transposed counts ----
__global__ void k2b_scan_cnts(int* __restrict__ cnts_t, int NC)
{
  int k = threadIdx.x;
  int run = 0;
  int* p = cnts_t + k * NC;
  for (int m = 0; m < NC; ++m) { int t = p[m]; p[m] = run; run += t; }
}

// ---- K3a: level-1 exclusive scan over 16 chunks, IN PLACE on bf16 sums ----
// Thread owns 2 adjacent columns (one uint); f32 accumulators; aux = f32 totals.
__global__ __launch_bounds__(256) void k3a_scan_lo(
    unsigned short* __restrict__ sums, float* __restrict__ aux)
{
  const int g  = blockIdx.x / 96;
  const int cp = (blockIdx.x % 96) * 256 + threadIdx.x;  // column pair
  const int col = cp * 2;
  float run0 = 0.f, run1 = 0.f;
  for (int m = g * 16; m < g * 16 + 16; ++m) {
    size_t idx = (size_t)m * (K * D) + col;
    unsigned u = *(const unsigned*)(sums + idx);
    float t0 = bflo(u), t1 = bfhi(u);
    *(unsigned*)(sums + idx) = (unsigned)f2bf(run0) | ((unsigned)f2bf(run1) << 16);
    run0 += t0; run1 += t1;
  }
  aux[(size_t)g * (K * D) + col]     = run0;
  aux[(size_t)g * (K * D) + col + 1] = run1;
}

// ---- K3b: scan group totals (f32) ----
__global__ __launch_bounds__(256) void k3b_scan_hi(float* __restrict__ aux)
{
  int col = blockIdx.x * 256 + threadIdx.x;
  float run = 0.f;
  for (int g = 0; g < 16; ++g) {
    size_t idx = (size_t)g * (K * D) + col;
    float t = aux[idx]; aux[idx] = run; run += t;
  }
}

// ---- K4v4: fused GEMMs + epilogue; bf16 base staging; pv from Gram diagonal ----
#define LDV2 136  // bf16 row stride for 128-col tiles
#define LDD  132  // f32 dot LDS stride
__global__ __launch_bounds__(512, 4) void k4_v4(
    const unsigned short* __restrict__ Vb, const unsigned short* __restrict__ base,
    const float* __restrict__ aux, const unsigned short* __restrict__ cavgb,
    const int* __restrict__ labels, const int* __restrict__ cnts_t,
    const float* __restrict__ cn2, float* __restrict__ out)
{
  __shared__ unsigned short smem[2 * 128 * LDV2];   // Vt | Bt; later f32 dot[128][LDD]
  __shared__ float pvL[128];
  __shared__ float bn2L[64];
  __shared__ int   labL[128];
  __shared__ float chk[8][64];
  unsigned short* Vt = smem;
  unsigned short* Bt = smem + 128 * LDV2;
  const int m = blockIdx.x;
  const int g = m >> 4;
  const int tid = threadIdx.x;
  const int w = tid >> 6, l = tid & 63;
  const int r31 = l & 31, kh = l >> 5;
  const int wr = w & 3;          // output row-tile (32 rows)
  const int wt = (w >> 2) * 2;   // output col-tile base

  if (tid < 128) labL[tid] = labels[m * 128 + tid];
  if (tid < 64) bn2L[tid] = 0.f;
  __syncthreads();

  f32x16 accP[2], accS[2];
  accP[0] = (f32x16){}; accP[1] = (f32x16){};
  accS[0] = (f32x16){}; accS[1] = (f32x16){};

  // V-tile prefetch registers (slab 0)
  uint4 vreg[4];
#pragma unroll
  for (int it = 0; it < 4; ++it) {
    int flat = it * 512 + tid;
    int row = flat >> 4, c = flat & 15;
    vreg[it] = *(const uint4*)(Vb + (size_t)(m * 128 + row) * D + c * 8);
  }

  for (int s = 0; s < 6; ++s) {
    // ---- write phase: V regs -> LDS; stage B' (bf16 base + f32 aux / cavgb) ----
#pragma unroll
    for (int it = 0; it < 4; ++it) {
      int flat = it * 512 + tid;
      int row = flat >> 4, c = flat & 15;
      *(uint4*)(Vt + row * LDV2 + c * 8) = vreg[it];
      if (row < 64) {
        uint4 ub = *(const uint4*)(base + ((size_t)m * K + row) * D + s * 128 + c * 8);
        const float* ap = aux + ((size_t)g * K + row) * D + s * 128 + c * 8;
        float4 af0 = *(const float4*)ap, af1 = *(const float4*)(ap + 4);
        float f0 = bflo(ub.x) + af0.x, f1 = bfhi(ub.x) + af0.y;
        float f2 = bflo(ub.y) + af0.z, f3 = bfhi(ub.y) + af0.w;
        float f4 = bflo(ub.z) + af1.x, f5 = bfhi(ub.z) + af1.y;
        float f6 = bflo(ub.w) + af1.z, f7 = bfhi(ub.w) + af1.w;
        float sq = f0*f0 + f1*f1 + f2*f2 + f3*f3 + f4*f4 + f5*f5 + f6*f6 + f7*f7;
        sq += __shfl_xor(sq, 1); sq += __shfl_xor(sq, 2);
        sq += __shfl_xor(sq, 4); sq += __shfl_xor(sq, 8);
        if ((l & 15) == 0) atomicAdd(&bn2L[row], sq);
        uint4 u;
        u.x = (unsigned)f2bf(f0) | ((unsigned)f2bf(f1) << 16);
        u.y = (unsigned)f2bf(f2) | ((unsigned)f2bf(f3) << 16);
        u.z = (unsigned)f2bf(f4) | ((unsigned)f2bf(f5) << 16);
        u.w = (unsigned)f2bf(f6) | ((unsigned)f2bf(f7) << 16);
        *(uint4*)(Bt + row * LDV2 + c * 8) = u;
      } else {
        *(uint4*)(Bt + row * LDV2 + c * 8) =
            *(const uint4*)(cavgb + (size_t)(row - 64) * D + s * 128 + c * 8);
      }
    }
    __syncthreads();
    // ---- issue next-slab V loads (latency hides under MFMA) ----
    if (s < 5) {
#pragma unroll
      for (int it = 0; it < 4; ++it) {
        int flat = it * 512 + tid;
        int row = flat >> 4, c = flat & 15;
        vreg[it] = *(const uint4*)(Vb + (size_t)(m * 128 + row) * D + (s + 1) * 128 + c * 8);
      }
    }
    // ---- MFMA on this slab ----
#pragma unroll
    for (int kk = 0; kk < 8; ++kk) {
      bf16x8 av = *(const bf16x8*)(Vt + (32 * wr + r31) * LDV2 + kk * 16 + kh * 8);
#pragma unroll
      for (int ti = 0; ti < 2; ++ti) {
        int t = wt + ti;
        bf16x8 bB = *(const bf16x8*)(Bt + (32 * t + r31) * LDV2 + kk * 16 + kh * 8);
        accP[ti] = __builtin_amdgcn_mfma_f32_32x32x16_bf16(av, bB, accP[ti], 0, 0, 0);
        bf16x8 bV = *(const bf16x8*)(Vt + (32 * t + r31) * LDV2 + kk * 16 + kh * 8);
        accS[ti] = __builtin_amdgcn_mfma_f32_32x32x16_bf16(av, bV, accS[ti], 0, 0, 0);
      }
    }
    __syncthreads();
  }

  // ---- pv from Gram diagonal: S[i][i] = ||v_bf16,i||^2 (before masking) ----
  {
    int ti_diag = (w == 0 || w == 6) ? 0 : (w == 1 || w == 7) ? 1 : -1;
    if (ti_diag >= 0 && wr == wt + ti_diag && ((r31 >> 2) & 1) == kh) {
      int q = (r31 & 3) + 4 * (r31 >> 3);
      pvL[32 * wr + r31] = accS[ti_diag][q];
    }
  }

  // ---- masked S -> bf16 into Vt region; one-hot Mt into Bt region ----
#pragma unroll
  for (int ti = 0; ti < 2; ++ti)
#pragma unroll
    for (int q = 0; q < 16; ++q) {
      int i = 32 * wr + (q & 3) + 8 * (q >> 2) + 4 * kh;
      int j = 32 * (wt + ti) + r31;
      Vt[i * LDV2 + j] = (j < i) ? f2bf(accS[ti][q]) : (unsigned short)0;
    }
  {
    int j = tid & 127;
    int lab = labL[j];
    int kb = (tid >> 7) * 16;
#pragma unroll
    for (int kk = 0; kk < 16; ++kk) {
      int k = kb + kk;
      Bt[k * LDV2 + j] = (lab == k) ? (unsigned short)0x3F80 : (unsigned short)0;
    }
  }
  __syncthreads();

  // ---- corr = tril_strict(S) @ onehot, into accP (class cols, waves 0-3) ----
  if (w < 4) {
#pragma unroll
    for (int kk = 0; kk < 8; ++kk) {
      bf16x8 aS = *(const bf16x8*)(Vt + (32 * wr + r31) * LDV2 + kk * 16 + kh * 8);
#pragma unroll
      for (int ti = 0; ti < 2; ++ti) {
        bf16x8 bM = *(const bf16x8*)(Bt + (32 * ti + r31) * LDV2 + kk * 16 + kh * 8);
        accP[ti] = __builtin_amdgcn_mfma_f32_32x32x16_bf16(aS, bM, accP[ti], 0, 0, 0);
      }
    }
  }
  __syncthreads();

  // ---- dot matrix -> LDS (overwrites tiles) ----
  float* dotL = (float*)smem;
#pragma unroll
  for (int ti = 0; ti < 2; ++ti)
#pragma unroll
    for (int q = 0; q < 16; ++q) {
      int i = 32 * wr + (q & 3) + 8 * (q >> 2) + 4 * kh;
      int col = 32 * (wt + ti) + r31;
      dotL[i * LDD + col] = accP[ti][q];
    }
  __syncthreads();

  // ---- wave 0: norm-recurrence checkpoints every 16 rows ----
  if (w == 0) {
    int k = l;
    bool seen = cnts_t[k * NCF + m] > 0;
    float n = seen ? bn2L[k] : 0.f;
    for (int seg = 0; seg < 8; ++seg) {
      chk[seg][k] = seen ? n : -1.f;
      if (seg == 7) break;
      for (int j = seg * 16; j < seg * 16 + 16; ++j) {
        float dS = dotL[j * LDD + k];
        float pvj = pvL[j];
        if (labL[j] == k) {
          n = seen ? (n + 2.f * dS + pvj) : pvj;
          seen = true;
        }
      }
    }
  }
  __syncthreads();

  // ---- all 8 waves: emit 16-row segment from checkpoint ----
  {
    int k = l;
    float st = chk[w][k];
    bool seen = st >= 0.f;
    float n = seen ? st : 0.f;
    float cnk = cn2[k];
    int jb = w * 16;
    for (int j = jb; j < jb + 16; ++j) {
      float dS = dotL[j * LDD + k];
      float dC = dotL[j * LDD + 64 + k];
      float pvj = pvL[j];
      int lab = labL[j];
      float val = seen ? dS : dC;
      float nn  = seen ? n : cnk;
      out[(size_t)(m * 128 + j) * K + k] = val * rsqrtf(fmaxf(nn * pvj, 1e-30f));
      if (lab == k) {
        n = seen ? (n + 2.f * dS + pvj) : pvj;
        seen = true;
      }
    }
  }
}

// =====================================================================
// FALLBACK PATH — round-1 pipeline, verbatim (known-correct)
// =====================================================================
__global__ __launch_bounds__(256) void ph1_chunk_sums(
    const float* __restrict__ inputs, const int* __restrict__ labels,
    float* __restrict__ sums, int* __restrict__ cnts, int NC, int C)
{
  __shared__ float acc[4 * K * 64];
  __shared__ int   hist[4 * K];
  const int bi    = blockIdx.x;
  const int chunk = bi / 12, slice = bi % 12;
  const int w = threadIdx.x >> 6, l = threadIdx.x & 63;

  for (int e = threadIdx.x; e < 4 * K * 64; e += 256) acc[e] = 0.f;
  hist[threadIdx.x] = 0;
  __syncthreads();

  const int C4 = C >> 2;
  const long long rbase = (long long)chunk * C + (long long)w * C4;
  float* accw = acc + w * (K * 64);
  for (int j = 0; j < C4; ++j) {
    long long r = rbase + j;
    int lab = labels[r];
    float v = inputs[r * D + slice * 64 + l];
    accw[lab * 64 + l] += v;
    if (slice == 0 && l == 0) hist[w * K + lab]++;
  }
  __syncthreads();

  float* sp = sums + (long long)chunk * (K * D) + slice * 64;
  for (int e = threadIdx.x; e < K * 64; e += 256) {
    int k = e >> 6, dl = e & 63;
    float s = acc[0*K*64 + e] + acc[1*K*64 + e] + acc[2*K*64 + e] + acc[3*K*64 + e];
    sp[k * D + dl] = s;
  }
  if (slice == 0 && threadIdx.x < K) {
    cnts[chunk * K + threadIdx.x] =
        hist[0*K + threadIdx.x] + hist[1*K + threadIdx.x] +
        hist[2*K + threadIdx.x] + hist[3*K + threadIdx.x];
  }
}

__global__ __launch_bounds__(256) void ph2a_scan_sums(float* __restrict__ sums, int NC)
{
  const int tid = blockIdx.x * 256 + threadIdx.x;
  float run = 0.f;
  for (int m = 0; m < NC; ++m) {
    long long idx = (long long)m * (K * D) + tid;
    float t = sums[idx];
    sums[idx] = run;
    run += t;
  }
}

__global__ void ph2b_scan_cnts(int* __restrict__ cnts, int NC)
{
  const int k = threadIdx.x;
  int run = 0;
  for (int m = 0; m < NC; ++m) {
    int t = cnts[m * K + k];
    cnts[m * K + k] = run;
    run += t;
  }
}

__global__ __launch_bounds__(256, 4) void ph3_scan(
    const float* __restrict__ inputs, const int* __restrict__ labels,
    const float* __restrict__ cavg, const float* __restrict__ base,
    const int* __restrict__ cnts, float* __restrict__ out, int NC, int C)
{
  const int bi = blockIdx.x;
  int chunk, quad;
  if (NC >= 8) {
    int xcd = bi & 7, slot = bi >> 3;
    chunk = xcd * (NC >> 3) + (slot >> 2);
    quad  = slot & 3;
  } else {
    chunk = bi >> 2; quad = bi & 3;
  }
  const int w = threadIdx.x >> 6, l = threadIdx.x & 63;
  const int k0 = (quad * 4 + w) * 4;

  const int cb = chunk * K + k0;
  bool vg0 = (cnts[cb+0] == 0), vg1 = (cnts[cb+1] == 0);
  bool vg2 = (cnts[cb+2] == 0), vg3 = (cnts[cb+3] == 0);

  const float4* bp = (const float4*)base + (long long)chunk * (K * D4);
  const float4* cp = (const float4*)cavg;

  float4 A0[3], A1[3], A2[3], A3[3];
#pragma unroll
  for (int t = 0; t < 3; ++t) {
    int o = t * 64 + l;
    A0[t] = vg0 ? cp[(k0+0)*D4 + o] : bp[(k0+0)*D4 + o];
    A1[t] = vg1 ? cp[(k0+1)*D4 + o] : bp[(k0+1)*D4 + o];
    A2[t] = vg2 ? cp[(k0+2)*D4 + o] : bp[(k0+2)*D4 + o];
    A3[t] = vg3 ? cp[(k0+3)*D4 + o] : bp[(k0+3)*D4 + o];
  }
  float n0 = 0.f, n1 = 0.f, n2 = 0.f, n3 = 0.f;
#pragma unroll
  for (int t = 0; t < 3; ++t) {
    n0 += d4f(A0[t], A0[t]); n1 += d4f(A1[t], A1[t]);
    n2 += d4f(A2[t], A2[t]); n3 += d4f(A3[t], A3[t]);
  }
#pragma unroll
  for (int m = 1; m <= 32; m <<= 1) {
    n0 += __shfl_xor(n0, m); n1 += __shfl_xor(n1, m);
    n2 += __shfl_xor(n2, m); n3 += __shfl_xor(n3, m);
  }

  const long long ibase = (long long)chunk * C;
  for (int j = 0; j < C; ++j) {
    const long long i = ibase + j;
    const int lab = labels[i];
    const float4* vp = (const float4*)inputs + i * D4;
    float4 v0 = vp[l], v1 = vp[64 + l], v2 = vp[128 + l];

    float p0 = d4f(A0[0], v0) + d4f(A0[1], v1) + d4f(A0[2], v2);
    float p1 = d4f(A1[0], v0) + d4f(A1[1], v1) + d4f(A1[2], v2);
    float p2 = d4f(A2[0], v0) + d4f(A2[1], v1) + d4f(A2[2], v2);
    float p3 = d4f(A3[0], v0) + d4f(A3[1], v1) + d4f(A3[2], v2);
    float pv = d4f(v0, v0) + d4f(v1, v1) + d4f(v2, v2);
#pragma unroll
    for (int m = 1; m <= 32; m <<= 1) {
      p0 += __shfl_xor(p0, m); p1 += __shfl_xor(p1, m);
      p2 += __shfl_xor(p2, m); p3 += __shfl_xor(p3, m);
      pv += __shfl_xor(pv, m);
    }
    if (l < 4) {
      float ps = (l == 0) ? p0 : (l == 1) ? p1 : (l == 2) ? p2 : p3;
      float ns = (l == 0) ? n0 : (l == 1) ? n1 : (l == 2) ? n2 : n3;
      out[i * K + k0 + l] = ps * rsqrtf(fmaxf(ns * pv, 1e-30f));
    }
#define UPD(idx) do { \
      if (vg##idx) { A##idx[0]=v0; A##idx[1]=v1; A##idx[2]=v2; n##idx = pv; vg##idx = false; } \
      else { A##idx[0]=a4(A##idx[0],v0); A##idx[1]=a4(A##idx[1],v1); A##idx[2]=a4(A##idx[2],v2); \
             n##idx += 2.f * p##idx + pv; } } while (0)
    if      (lab == k0 + 0) UPD(0);
    else if (lab == k0 + 1) UPD(1);
    else if (lab == k0 + 2) UPD(2);
    else if (lab == k0 + 3) UPD(3);
#undef UPD
  }
}

// =====================================================================
extern "C" void kernel_launch(void* const* d_in, const int* in_sizes, int n_in,
                              void* d_out, int out_size, void* d_ws, size_t ws_size,
                              hipStream_t stream)
{
  const float* inputs = (const float*)d_in[0];
  const int*   labels = (const int*)d_in[1];
  const float* cavg   = (const float*)d_in[2];
  float* out = (float*)d_out;
  const int N = in_sizes[1];

  const size_t szVb    = (size_t)NF * D * 2;      // 50.3 MB
  const size_t szSums  = (size_t)NCF * K * D * 2; // 25.2 MB (bf16, scanned in place)
  const size_t szAux   = (size_t)16 * K * D * 4;  // 3.1 MB
  const size_t szCnt   = (size_t)K * NCF * 4;
  const size_t szCavgb = (size_t)K * D * 2;
  const size_t szCn2   = (size_t)K * 4;
  size_t need = szVb + szSums + szAux + szCnt + szCavgb + szCn2 + 8 * 256;

  if (N == NF && in_sizes[2] == K * D && ws_size >= need) {
    char* p = (char*)d_ws;
    auto take = [&](size_t b) { char* r = p; p += (b + 255) & ~(size_t)255; return r; };
    unsigned short* Vb    = (unsigned short*)take(szVb);
    unsigned short* sums  = (unsigned short*)take(szSums);
    float*          aux   = (float*)take(szAux);
    int*            cnts  = (int*)take(szCnt);
    unsigned short* cavgb = (unsigned short*)take(szCavgb);
    float*          cn2   = (float*)take(szCn2);

    hipLaunchKernelGGL(k1c, dim3(16), dim3(256), 0, stream, cavg, cavgb, cn2);
    hipLaunchKernelGGL(k2_v4, dim3(NCF * 3), dim3(256), 0, stream,
                       inputs, labels, Vb, sums, cnts);
    hipLaunchKernelGGL(k2b_scan_cnts, dim3(1), dim3(K), 0, stream, cnts, NCF);
    hipLaunchKernelGGL(k3a_scan_lo, dim3(16 * 96), dim3(256), 0, stream, sums, aux);
    hipLaunchKernelGGL(k3b_scan_hi, dim3(192), dim3(256), 0, stream, aux);
    hipLaunchKernelGGL(k4_v4, dim3(NCF), dim3(512), 0, stream,
                       Vb, sums, aux, cavgb, labels, cnts, cn2, out);
    return;
  }

  // ---------------- fallback: round-1 pipeline ----------------
  int NC = 256;
  while (NC > 1) {
    size_t nd = (size_t)NC * K * D * 4 + (size_t)NC * K * 4;
    if (nd <= ws_size && (N % (NC * 4)) == 0) break;
    NC >>= 1;
  }
  const int C = N / NC;
  float* d_sums = (float*)d_ws;
  int*   d_cnts = (int*)((char*)d_ws + (size_t)NC * K * D * 4);

  hipLaunchKernelGGL(ph1_chunk_sums, dim3(NC * 12), dim3(256), 0, stream,
                     inputs, labels, d_sums, d_cnts, NC, C);
  hipLaunchKernelGGL(ph2a_scan_sums, dim3((K * D) / 256), dim3(256), 0, stream,
                     d_sums, NC);
  hipLaunchKernelGGL(ph2b_scan_cnts, dim3(1), dim3(64), 0, stream,
                     d_cnts, NC);
  hipLaunchKernelGGL(ph3_scan, dim3(NC * 4), dim3(256), 0, stream,
                     inputs, labels, cavg, d_sums, d_cnts, out, NC, C);
}